// Round 5
// baseline (7100.409 us; speedup 1.0000x reference)
//
#include <hip/hip_runtime.h>

typedef unsigned short u16;
typedef __attribute__((ext_vector_type(8))) short short8;
typedef __attribute__((ext_vector_type(4))) short short4v;
typedef __attribute__((ext_vector_type(4))) float f32x4;

#define B_    64
#define S_    512
#define E_    512
#define H_    512
#define NSEG_ 64

// ---------- helpers ----------
__device__ __forceinline__ float bf2f(u16 u) {
    union { unsigned int i; float f; } x; x.i = ((unsigned int)u) << 16; return x.f;
}
__device__ __forceinline__ u16 f2bf(float f) {
    union { float f; unsigned int i; } x; x.f = f;
    unsigned int r = x.i + 0x7fffu + ((x.i >> 16) & 1u);
    return (u16)(r >> 16);
}
__device__ __forceinline__ f32x4 mfma16(short8 a, short8 b, f32x4 c) {
    return __builtin_amdgcn_mfma_f32_16x16x32_bf16(a, b, c, 0, 0, 0);
}
__device__ __forceinline__ float sigmoidf_(float x) { return 1.f / (1.f + __expf(-x)); }
__device__ __forceinline__ float tanhf_(float x) {
    float e = __expf(-2.f * fabsf(x));
    float t = (1.f - e) / (1.f + e);
    return x < 0.f ? -t : t;
}

// workspace layout (bytes) — all inputs are FP32; bf16 copies live in ws.
#define EMBB_OFF  0
#define WIHB_OFF  51200000
#define WHHB_OFF  54345728
#define HBUF_OFF  57491456
#define CNT_OFF   57753600
#define XP_OFF    57757696

// ---------- prep: fp32 -> bf16 conversions + zero hbuf/counters ----------
__global__ __launch_bounds__(256) void prep_kernel(
    const float* __restrict__ emb,
    const float* __restrict__ wih_f, const float* __restrict__ whh_f,
    const float* __restrict__ wih_b, const float* __restrict__ whh_b,
    u16* __restrict__ embb, u16* __restrict__ wihbb, u16* __restrict__ whhbb,
    u16* __restrict__ hbuf, int* __restrict__ cnt)
{
    const int nt = gridDim.x * 256;
    const int i = blockIdx.x * 256 + threadIdx.x;

    const float4* e4 = (const float4*)emb;
    short4v* eo = (short4v*)embb;
    for (int k = i; k < 6400000; k += nt) {
        float4 v = e4[k];
        short4v o = { (short)f2bf(v.x), (short)f2bf(v.y), (short)f2bf(v.z), (short)f2bf(v.w) };
        eo[k] = o;
    }
    const float4* wf[4] = { (const float4*)wih_f, (const float4*)wih_b,
                            (const float4*)whh_f, (const float4*)whh_b };
    short4v* wo[4] = { (short4v*)wihbb, (short4v*)(wihbb + 786432),
                       (short4v*)whhbb, (short4v*)(whhbb + 786432) };
#pragma unroll
    for (int a = 0; a < 4; ++a) {
        for (int k = i; k < 196608; k += nt) {
            float4 v = wf[a][k];
            short4v o = { (short)f2bf(v.x), (short)f2bf(v.y), (short)f2bf(v.z), (short)f2bf(v.w) };
            wo[a][k] = o;
        }
    }
    int* hz = (int*)hbuf;
    for (int k = i; k < 65536; k += nt) hz[k] = 0;
    for (int k = i; k < 1024; k += nt) cnt[k] = 0;
}

// ---------- input projection: xp = emb[seq] @ w_ih_d^T + b_ih_d ----------
__global__ __launch_bounds__(256) void proj_kernel(
    const int* __restrict__ seq, const u16* __restrict__ embb,
    const u16* __restrict__ wihbb,
    const float* __restrict__ b_ih_f, const float* __restrict__ b_ih_b,
    u16* __restrict__ xp)
{
    const int bid = blockIdx.x;            // 256 * 24
    const int mt = bid / 24, nt = bid % 24;
    const int tid = threadIdx.x;
    const int w = tid >> 6, l = tid & 63;
    const int q = l >> 4, col = l & 15;
    const int M0 = mt * 128 + (w >> 1) * 64;
    const int N0 = nt * 128 + (w & 1) * 64;

    const u16* arow[4];
#pragma unroll
    for (int ai = 0; ai < 4; ++ai) {
        const int tok = seq[M0 + ai * 16 + col];
        arow[ai] = embb + (long)tok * E_;
    }
    const u16* brow[4];
#pragma unroll
    for (int bi = 0; bi < 4; ++bi)
        brow[bi] = wihbb + (long)(N0 + bi * 16 + col) * E_;

    f32x4 acc[4][4];
#pragma unroll
    for (int ai = 0; ai < 4; ++ai)
#pragma unroll
        for (int bi = 0; bi < 4; ++bi) acc[ai][bi] = (f32x4){0,0,0,0};

    for (int k = 0; k < 16; ++k) {
        const int ko = k * 32 + q * 8;
        short8 a[4], b[4];
#pragma unroll
        for (int ai = 0; ai < 4; ++ai) a[ai] = *(const short8*)(arow[ai] + ko);
#pragma unroll
        for (int bi = 0; bi < 4; ++bi) b[bi] = *(const short8*)(brow[bi] + ko);
#pragma unroll
        for (int ai = 0; ai < 4; ++ai)
#pragma unroll
            for (int bi = 0; bi < 4; ++bi)
                acc[ai][bi] = mfma16(a[ai], b[bi], acc[ai][bi]);
    }

#pragma unroll
    for (int bi = 0; bi < 4; ++bi) {
        const int n = N0 + bi * 16 + col;
        const int dir = (n >= 1536) ? 1 : 0;
        const int j = n - dir * 1536;
        const int g = j >> 9, u = j & 511, uc = u >> 4;
        const float bias = dir ? b_ih_b[j] : b_ih_f[j];
        const long base = (long)(dir * 32 + uc) * (64L * 512 * 48) + g * 16 + col;
#pragma unroll
        for (int ai = 0; ai < 4; ++ai) {
#pragma unroll
            for (int i = 0; i < 4; ++i) {
                const int m = M0 + ai * 16 + q * 4 + i;
                const int bs = m >> 9, s = m & 511;
                xp[base + ((long)bs * 512 + s) * 48] = f2bf(acc[ai][bi][i] + bias);
            }
        }
    }
}

// ---------- recurrence + fused segment max ----------
// 32 wgs of 512 threads = 2 dirs x 4 sample-groups x 4 unit-chunks.
// Each wave owns 16 units (192 VGPR of W_hh); wg covers 16 samples x 128 units.
// Barrier domain = the 4 wgs sharing (dir, sample-group): ONE monotone counter,
// 4 relaxed arrivals, coalesced single-address polling with s_sleep backoff.
// h exchange: write-through system stores -> syncthreads (vmcnt drain) ->
// counter add; consumers: poll -> acquire (buffer_inv) -> plain loads.
__global__ __launch_bounds__(512, 2) void rnn_kernel(
    const int* __restrict__ lens, const int* __restrict__ layout,
    const u16* __restrict__ whhbb,
    const float* __restrict__ b_hh_f, const float* __restrict__ b_hh_b,
    const u16* __restrict__ xp, u16* __restrict__ hbuf, int* __restrict__ cnt,
    float* __restrict__ out)
{
    const int bid = blockIdx.x;            // 32 = dir(2) x group(4) x chunk(4)
    const int dir   = bid >> 4;
    const int g     = (bid >> 2) & 3;
    const int chunk = bid & 3;
    const int tid = threadIdx.x;
    const int w = tid >> 6, l = tid & 63;
    const int q = l >> 4, col = l & 15;
    const int uc = chunk * 8 + w;          // global 16-unit chunk 0..31
    const int u0 = uc * 16;
    const int u  = u0 + col;

    // preload this wave's W_hh slice as MFMA B-fragments: 16 ksteps x 3 gates
    const u16* Whh = whhbb + (long)dir * (3 * H_ * H_);
    short8 wreg[16][3];
#pragma unroll
    for (int k = 0; k < 16; ++k)
#pragma unroll
        for (int gg = 0; gg < 3; ++gg)
            wreg[k][gg] = *(const short8*)(Whh + (long)(gg * 512 + u0 + col) * H_ + k * 32 + q * 8);

    const float* bhh = dir ? b_hh_b : b_hh_f;
    const float bh0 = bhh[0 * 512 + u];
    const float bh1 = bhh[1 * 512 + u];
    const float bh2 = bhh[2 * 512 + u];

    int samp[4], Ls[4], seg[4], bnd[4];
    float hm[4], mx[4];
    bool done[4];
#pragma unroll
    for (int i = 0; i < 4; ++i) {
        samp[i] = g * 16 + q * 4 + i;
        Ls[i] = lens[samp[i]];
        hm[i] = 0.f;
        mx[i] = -3.4e38f;
        done[i] = false;
        if (dir == 0) { seg[i] = 0; bnd[i] = layout[samp[i] * 65 + 1]; }
        else          { seg[i] = 63; bnd[i] = layout[samp[i] * 65 + 63]; }
    }
    const int asamp = g * 16 + col;        // A-fragment row (sample)

    const u16* xpb = xp + (long)(dir * 32 + uc) * (64L * 512 * 48);
    u16* hb_base = hbuf + (long)dir * 2 * B_ * H_;
    int* gc = cnt + (dir * 4 + g) * 32;    // group counter, own cacheline

    // xp gate inputs for the CURRENT step (software-pipelined)
    u16 cxr[4], cxz[4], cxn[4];
    int cpv[4]; bool cval[4];
#pragma unroll
    for (int i = 0; i < 4; ++i) {
        const int L = Ls[i];
        cval[i] = (0 < L);
        int p = dir ? (L - 1) : 0;
        if (p < 0) p = 0;
        cpv[i] = p;
        const u16* xq = xpb + ((long)samp[i] * 512 + p) * 48;
        cxr[i] = xq[0 * 16 + col];
        cxz[i] = xq[1 * 16 + col];
        cxn[i] = xq[2 * 16 + col];
    }

    for (int t = 0; t < 512; ++t) {
        // prefetch next step's xp BEFORE the poll (barrier-independent;
        // its IF latency hides under the wait)
        u16 nxr[4], nxz[4], nxn[4];
        int npv[4]; bool nval[4];
        const int tn = t + 1;
        if (tn < 512) {
#pragma unroll
            for (int i = 0; i < 4; ++i) {
                const int L = Ls[i];
                nval[i] = (tn < L);
                int p = dir ? (L - 1 - tn) : tn;
                if (p < 0) p = 0;
                npv[i] = p;
                const u16* xq = xpb + ((long)samp[i] * 512 + p) * 48;
                nxr[i] = xq[0 * 16 + col];
                nxz[i] = xq[1 * 16 + col];
                nxn[i] = xq[2 * 16 + col];
            }
        } else {
#pragma unroll
            for (int i = 0; i < 4; ++i) { nxr[i] = nxz[i] = nxn[i] = 0; npv[i] = 0; nval[i] = false; }
        }

        if (t > 0) {
            // wait for the 4 wgs of this (dir, sample-group) domain
            const int target = 4 * t;
            while (__hip_atomic_load(gc, __ATOMIC_RELAXED, __HIP_MEMORY_SCOPE_SYSTEM) < target)
                __builtin_amdgcn_s_sleep(1);
            (void)__hip_atomic_load(gc, __ATOMIC_ACQUIRE, __HIP_MEMORY_SCOPE_SYSTEM);
        }

        // gh = h_prev @ W_chunk^T (fp32 accum) — plain loads fresh post-inv
        const u16* hr = hb_base + (long)(t & 1) * B_ * H_ + (long)asamp * H_;
        f32x4 ar = {0,0,0,0}, az = {0,0,0,0}, an = {0,0,0,0};
#pragma unroll
        for (int k = 0; k < 16; ++k) {
            short8 a = *(const short8*)(hr + k * 32 + q * 8);
            ar = mfma16(a, wreg[k][0], ar);
            az = mfma16(a, wreg[k][1], az);
            an = mfma16(a, wreg[k][2], an);
        }

        // gates + state update (critical path)
        float hnv[4];
#pragma unroll
        for (int i = 0; i < 4; ++i) {
            const float r = sigmoidf_(bf2f(cxr[i]) + ar[i] + bh0);
            const float z = sigmoidf_(bf2f(cxz[i]) + az[i] + bh1);
            const float n = tanhf_(bf2f(cxn[i]) + r * (an[i] + bh2));
            const float hnew = (1.f - z) * n + z * hm[i];
            if (cval[i]) hm[i] = hnew;
            hnv[i] = hnew;
        }

        // packed write-through h store immediately (chain-critical)
        u16* hw = hb_base + (long)((t + 1) & 1) * B_ * H_;
#pragma unroll
        for (int i = 0; i < 4; ++i) {
            const float other = __shfl_xor(hm[i], 1);
            if ((col & 1) == 0) {
                const unsigned int pk = ((unsigned int)f2bf(other) << 16) | (unsigned int)f2bf(hm[i]);
                __hip_atomic_store((unsigned int*)(hw + (long)samp[i] * H_ + u), pk,
                                   __ATOMIC_RELAXED, __HIP_MEMORY_SCOPE_SYSTEM);
            }
        }

        // off-chain: fused ragged segment-max bookkeeping
#pragma unroll
        for (int i = 0; i < 4; ++i) {
            if (cval[i]) {
                if (dir == 0) {
                    while (t >= bnd[i] && seg[i] < 63) {
                        out[((long)samp[i] * 64 + seg[i]) * 1024 + u] = mx[i];
                        seg[i]++;
                        bnd[i] = layout[samp[i] * 65 + seg[i] + 1];
                        mx[i] = -3.4e38f;
                    }
                } else {
                    while (cpv[i] < bnd[i] && seg[i] > 0) {
                        out[((long)samp[i] * 64 + seg[i]) * 1024 + 512 + u] = mx[i];
                        seg[i]--;
                        bnd[i] = layout[samp[i] * 65 + seg[i]];
                        mx[i] = -3.4e38f;
                    }
                }
                mx[i] = fmaxf(mx[i], hnv[i]);
            } else if (!done[i]) {
                out[((long)samp[i] * 64 + seg[i]) * 1024 + dir * 512 + u] = mx[i];
                done[i] = true;
            }
        }

        // rotate pipelined xp regs
#pragma unroll
        for (int i = 0; i < 4; ++i) {
            cxr[i] = nxr[i]; cxz[i] = nxz[i]; cxn[i] = nxn[i];
            cpv[i] = npv[i]; cval[i] = nval[i];
        }

        // publish: all waves' stores drained by syncthreads, then 1 arrival add
        __syncthreads();
        if (tid == 0)
            __hip_atomic_fetch_add(gc, 1, __ATOMIC_RELAXED, __HIP_MEMORY_SCOPE_SYSTEM);
    }

#pragma unroll
    for (int i = 0; i < 4; ++i) {
        if (!done[i])  // full-length samples: flush last segment
            out[((long)samp[i] * 64 + seg[i]) * 1024 + dir * 512 + u] = mx[i];
        // final hidden: out[4194304 + dir*B*H + b*H + u]
        out[4194304 + dir * (B_ * H_) + samp[i] * H_ + u] = hm[i];
    }
}

// ---------- launch ----------
extern "C" void kernel_launch(void* const* d_in, const int* in_sizes, int n_in,
                              void* d_out, int out_size, void* d_ws, size_t ws_size,
                              hipStream_t stream) {
    const int*   seq    = (const int*)d_in[0];
    const int*   lens   = (const int*)d_in[1];
    const int*   layout = (const int*)d_in[3];
    const float* emb    = (const float*)d_in[4];
    const float* w_ih_f = (const float*)d_in[5];
    const float* w_hh_f = (const float*)d_in[6];
    const float* b_ih_f = (const float*)d_in[7];
    const float* b_hh_f = (const float*)d_in[8];
    const float* w_ih_b = (const float*)d_in[9];
    const float* w_hh_b = (const float*)d_in[10];
    const float* b_ih_b = (const float*)d_in[11];
    const float* b_hh_b = (const float*)d_in[12];
    float* out = (float*)d_out;
    char* ws = (char*)d_ws;

    u16* embb  = (u16*)(ws + EMBB_OFF);
    u16* wihbb = (u16*)(ws + WIHB_OFF);
    u16* whhbb = (u16*)(ws + WHHB_OFF);
    u16* hbuf  = (u16*)(ws + HBUF_OFF);
    int* cnt   = (int*)(ws + CNT_OFF);
    u16* xp    = (u16*)(ws + XP_OFF);

    prep_kernel<<<2048, 256, 0, stream>>>(emb, w_ih_f, w_hh_f, w_ih_b, w_hh_b,
                                          embb, wihbb, whhbb, hbuf, cnt);
    proj_kernel<<<256 * 24, 256, 0, stream>>>(seq, embb, wihbb, b_ih_f, b_ih_b, xp);
    rnn_kernel<<<32, 512, 0, stream>>>(lens, layout, whhbb, b_hh_f, b_hh_b,
                                       xp, hbuf, cnt, out);
}

// Round 6
// 2585.138 us; speedup vs baseline: 2.7466x; 2.7466x over previous
//
#include <hip/hip_runtime.h>

typedef unsigned short u16;
typedef __attribute__((ext_vector_type(8))) short short8;
typedef __attribute__((ext_vector_type(4))) short short4v;
typedef __attribute__((ext_vector_type(4))) float f32x4;

#define B_    64
#define S_    512
#define E_    512
#define H_    512
#define NSEG_ 64

// ---------- helpers ----------
__device__ __forceinline__ float bf2f(u16 u) {
    union { unsigned int i; float f; } x; x.i = ((unsigned int)u) << 16; return x.f;
}
__device__ __forceinline__ u16 f2bf(float f) {
    union { float f; unsigned int i; } x; x.f = f;
    unsigned int r = x.i + 0x7fffu + ((x.i >> 16) & 1u);
    return (u16)(r >> 16);
}
__device__ __forceinline__ f32x4 mfma16(short8 a, short8 b, f32x4 c) {
    return __builtin_amdgcn_mfma_f32_16x16x32_bf16(a, b, c, 0, 0, 0);
}
__device__ __forceinline__ float sigmoidf_(float x) { return 1.f / (1.f + __expf(-x)); }
__device__ __forceinline__ float tanhf_(float x) {
    float e = __expf(-2.f * fabsf(x));
    float t = (1.f - e) / (1.f + e);
    return x < 0.f ? -t : t;
}

// workspace layout (bytes) — all inputs are FP32; bf16 copies live in ws.
#define EMBB_OFF  0
#define WIHB_OFF  51200000
#define WHHB_OFF  54345728
#define HBUF_OFF  57491456
#define CNT_OFF   57753600
#define XP_OFF    57757696

// ---------- prep: fp32 -> bf16 conversions + zero hbuf/flags ----------
__global__ __launch_bounds__(256) void prep_kernel(
    const float* __restrict__ emb,
    const float* __restrict__ wih_f, const float* __restrict__ whh_f,
    const float* __restrict__ wih_b, const float* __restrict__ whh_b,
    u16* __restrict__ embb, u16* __restrict__ wihbb, u16* __restrict__ whhbb,
    u16* __restrict__ hbuf, int* __restrict__ cnt)
{
    const int nt = gridDim.x * 256;
    const int i = blockIdx.x * 256 + threadIdx.x;

    const float4* e4 = (const float4*)emb;
    short4v* eo = (short4v*)embb;
    for (int k = i; k < 6400000; k += nt) {
        float4 v = e4[k];
        short4v o = { (short)f2bf(v.x), (short)f2bf(v.y), (short)f2bf(v.z), (short)f2bf(v.w) };
        eo[k] = o;
    }
    const float4* wf[4] = { (const float4*)wih_f, (const float4*)wih_b,
                            (const float4*)whh_f, (const float4*)whh_b };
    short4v* wo[4] = { (short4v*)wihbb, (short4v*)(wihbb + 786432),
                       (short4v*)whhbb, (short4v*)(whhbb + 786432) };
#pragma unroll
    for (int a = 0; a < 4; ++a) {
        for (int k = i; k < 196608; k += nt) {
            float4 v = wf[a][k];
            short4v o = { (short)f2bf(v.x), (short)f2bf(v.y), (short)f2bf(v.z), (short)f2bf(v.w) };
            wo[a][k] = o;
        }
    }
    int* hz = (int*)hbuf;
    for (int k = i; k < 65536; k += nt) hz[k] = 0;
    for (int k = i; k < 1024; k += nt) cnt[k] = 0;
}

// ---------- input projection: xp = emb[seq] @ w_ih_d^T + b_ih_d ----------
__global__ __launch_bounds__(256) void proj_kernel(
    const int* __restrict__ seq, const u16* __restrict__ embb,
    const u16* __restrict__ wihbb,
    const float* __restrict__ b_ih_f, const float* __restrict__ b_ih_b,
    u16* __restrict__ xp)
{
    const int bid = blockIdx.x;            // 256 * 24
    const int mt = bid / 24, nt = bid % 24;
    const int tid = threadIdx.x;
    const int w = tid >> 6, l = tid & 63;
    const int q = l >> 4, col = l & 15;
    const int M0 = mt * 128 + (w >> 1) * 64;
    const int N0 = nt * 128 + (w & 1) * 64;

    const u16* arow[4];
#pragma unroll
    for (int ai = 0; ai < 4; ++ai) {
        const int tok = seq[M0 + ai * 16 + col];
        arow[ai] = embb + (long)tok * E_;
    }
    const u16* brow[4];
#pragma unroll
    for (int bi = 0; bi < 4; ++bi)
        brow[bi] = wihbb + (long)(N0 + bi * 16 + col) * E_;

    f32x4 acc[4][4];
#pragma unroll
    for (int ai = 0; ai < 4; ++ai)
#pragma unroll
        for (int bi = 0; bi < 4; ++bi) acc[ai][bi] = (f32x4){0,0,0,0};

    for (int k = 0; k < 16; ++k) {
        const int ko = k * 32 + q * 8;
        short8 a[4], b[4];
#pragma unroll
        for (int ai = 0; ai < 4; ++ai) a[ai] = *(const short8*)(arow[ai] + ko);
#pragma unroll
        for (int bi = 0; bi < 4; ++bi) b[bi] = *(const short8*)(brow[bi] + ko);
#pragma unroll
        for (int ai = 0; ai < 4; ++ai)
#pragma unroll
            for (int bi = 0; bi < 4; ++bi)
                acc[ai][bi] = mfma16(a[ai], b[bi], acc[ai][bi]);
    }

#pragma unroll
    for (int bi = 0; bi < 4; ++bi) {
        const int n = N0 + bi * 16 + col;
        const int dir = (n >= 1536) ? 1 : 0;
        const int j = n - dir * 1536;
        const int g = j >> 9, u = j & 511, uc = u >> 4;
        const float bias = dir ? b_ih_b[j] : b_ih_f[j];
        const long base = (long)(dir * 32 + uc) * (64L * 512 * 48) + g * 16 + col;
#pragma unroll
        for (int ai = 0; ai < 4; ++ai) {
#pragma unroll
            for (int i = 0; i < 4; ++i) {
                const int m = M0 + ai * 16 + q * 4 + i;
                const int bs = m >> 9, s = m & 511;
                xp[base + ((long)bs * 512 + s) * 48] = f2bf(acc[ai][bi][i] + bias);
            }
        }
    }
}

// ---------- recurrence + fused segment max ----------
// 256 wgs of 64 threads (1 wave each) = 2 dirs x 4 sample-groups x 32 chunks.
// Barrier domain = (dir, group): 32 wave-flags in one 128B line. Arrival =
// relaxed store after s_waitcnt vmcnt(0) (own write-through h stores ack'ed).
// Detection = lanes 0..31 load the flag line + ballot, s_sleep backoff.
// No __syncthreads anywhere in the loop: waves fully autonomous.
__global__ __launch_bounds__(64, 1) void rnn_kernel(
    const int* __restrict__ lens, const int* __restrict__ layout,
    const u16* __restrict__ whhbb,
    const float* __restrict__ b_hh_f, const float* __restrict__ b_hh_b,
    const u16* __restrict__ xp, u16* __restrict__ hbuf, int* __restrict__ cnt,
    float* __restrict__ out)
{
    const int bid = blockIdx.x;            // 256 = dir(2) x group(4) x chunk(32)
    const int dir = bid >> 7;
    const int g   = (bid >> 5) & 3;
    const int uc  = bid & 31;
    const int u0  = uc * 16;
    const int l = threadIdx.x;             // one wave
    const int q = l >> 4, col = l & 15;
    const int u = u0 + col;

    // preload this wave's W_hh slice as MFMA B-fragments: 16 ksteps x 3 gates
    const u16* Whh = whhbb + (long)dir * (3 * H_ * H_);
    short8 wreg[16][3];
#pragma unroll
    for (int k = 0; k < 16; ++k)
#pragma unroll
        for (int gg = 0; gg < 3; ++gg)
            wreg[k][gg] = *(const short8*)(Whh + (long)(gg * 512 + u0 + col) * H_ + k * 32 + q * 8);

    const float* bhh = dir ? b_hh_b : b_hh_f;
    const float bh0 = bhh[0 * 512 + u];
    const float bh1 = bhh[1 * 512 + u];
    const float bh2 = bhh[2 * 512 + u];

    int samp[4], Ls[4], seg[4], bnd[4];
    float hm[4], mx[4];
    bool done[4];
#pragma unroll
    for (int i = 0; i < 4; ++i) {
        samp[i] = g * 16 + q * 4 + i;
        Ls[i] = lens[samp[i]];
        hm[i] = 0.f;
        mx[i] = -3.4e38f;
        done[i] = false;
        if (dir == 0) { seg[i] = 0; bnd[i] = layout[samp[i] * 65 + 1]; }
        else          { seg[i] = 63; bnd[i] = layout[samp[i] * 65 + 63]; }
    }
    const int asamp = g * 16 + col;        // A-fragment row (sample)

    const u16* xpb = xp + (long)(dir * 32 + uc) * (64L * 512 * 48);
    u16* hb_base = hbuf + (long)dir * 2 * B_ * H_;
    int* fl = cnt + (dir * 4 + g) * 32;    // 32 wave-flags, one cacheline

    // xp gate inputs for the CURRENT step (software-pipelined)
    u16 cxr[4], cxz[4], cxn[4];
    int cpv[4]; bool cval[4];
#pragma unroll
    for (int i = 0; i < 4; ++i) {
        const int L = Ls[i];
        cval[i] = (0 < L);
        int p = dir ? (L - 1) : 0;
        if (p < 0) p = 0;
        cpv[i] = p;
        const u16* xq = xpb + ((long)samp[i] * 512 + p) * 48;
        cxr[i] = xq[0 * 16 + col];
        cxz[i] = xq[1 * 16 + col];
        cxn[i] = xq[2 * 16 + col];
    }

    for (int t = 0; t < 512; ++t) {
        if (t > 0) {
            // wait for all 32 waves of this (dir,group) domain: flags >= t
            unsigned long long rdy;
            do {
                const int v = __hip_atomic_load(&fl[l & 31], __ATOMIC_RELAXED,
                                                __HIP_MEMORY_SCOPE_SYSTEM);
                rdy = __ballot((l >= 32) || (v >= t));
                if (rdy != ~0ULL) __builtin_amdgcn_s_sleep(1);
            } while (rdy != ~0ULL);
            // acquire: invalidate stale cached h before plain loads
            (void)__hip_atomic_load(&fl[0], __ATOMIC_ACQUIRE, __HIP_MEMORY_SCOPE_SYSTEM);
        }

        // h loads (plain, fresh post-acquire)
        const u16* hr = hb_base + (long)(t & 1) * B_ * H_ + (long)asamp * H_;
        short8 afrag[16];
#pragma unroll
        for (int k = 0; k < 16; ++k)
            afrag[k] = *(const short8*)(hr + k * 32 + q * 8);

        // xp prefetch for t+1 issued early: lands during MFMA+gates, so the
        // post-store s_waitcnt vmcnt(0) doesn't stall on it
        u16 nxr[4], nxz[4], nxn[4];
        int npv[4]; bool nval[4];
        const int tn = t + 1;
        if (tn < 512) {
#pragma unroll
            for (int i = 0; i < 4; ++i) {
                const int L = Ls[i];
                nval[i] = (tn < L);
                int p = dir ? (L - 1 - tn) : tn;
                if (p < 0) p = 0;
                npv[i] = p;
                const u16* xq = xpb + ((long)samp[i] * 512 + p) * 48;
                nxr[i] = xq[0 * 16 + col];
                nxz[i] = xq[1 * 16 + col];
                nxn[i] = xq[2 * 16 + col];
            }
        } else {
#pragma unroll
            for (int i = 0; i < 4; ++i) { nxr[i] = nxz[i] = nxn[i] = 0; npv[i] = 0; nval[i] = false; }
        }

        f32x4 ar = {0,0,0,0}, az = {0,0,0,0}, an = {0,0,0,0};
#pragma unroll
        for (int k = 0; k < 16; ++k) {
            ar = mfma16(afrag[k], wreg[k][0], ar);
            az = mfma16(afrag[k], wreg[k][1], az);
            an = mfma16(afrag[k], wreg[k][2], an);
        }

        // gates + state update (critical path)
        float hnv[4];
#pragma unroll
        for (int i = 0; i < 4; ++i) {
            const float r = sigmoidf_(bf2f(cxr[i]) + ar[i] + bh0);
            const float z = sigmoidf_(bf2f(cxz[i]) + az[i] + bh1);
            const float n = tanhf_(bf2f(cxn[i]) + r * (an[i] + bh2));
            const float hnew = (1.f - z) * n + z * hm[i];
            if (cval[i]) hm[i] = hnew;
            hnv[i] = hnew;
        }

        // packed write-through h store (chain-critical)
        u16* hw = hb_base + (long)((t + 1) & 1) * B_ * H_;
#pragma unroll
        for (int i = 0; i < 4; ++i) {
            const float other = __shfl_xor(hm[i], 1);
            if ((col & 1) == 0) {
                const unsigned int pk = ((unsigned int)f2bf(other) << 16) | (unsigned int)f2bf(hm[i]);
                __hip_atomic_store((unsigned int*)(hw + (long)samp[i] * H_ + u), pk,
                                   __ATOMIC_RELAXED, __HIP_MEMORY_SCOPE_SYSTEM);
            }
        }

        // drain own stores (and the already-landed prefetch), then publish
        asm volatile("s_waitcnt vmcnt(0)" ::: "memory");
        if (l == 0)
            __hip_atomic_store(&fl[uc], t + 1, __ATOMIC_RELAXED, __HIP_MEMORY_SCOPE_SYSTEM);

        // off-chain: fused ragged segment-max bookkeeping (after publish)
#pragma unroll
        for (int i = 0; i < 4; ++i) {
            if (cval[i]) {
                if (dir == 0) {
                    while (t >= bnd[i] && seg[i] < 63) {
                        out[((long)samp[i] * 64 + seg[i]) * 1024 + u] = mx[i];
                        seg[i]++;
                        bnd[i] = layout[samp[i] * 65 + seg[i] + 1];
                        mx[i] = -3.4e38f;
                    }
                } else {
                    while (cpv[i] < bnd[i] && seg[i] > 0) {
                        out[((long)samp[i] * 64 + seg[i]) * 1024 + 512 + u] = mx[i];
                        seg[i]--;
                        bnd[i] = layout[samp[i] * 65 + seg[i]];
                        mx[i] = -3.4e38f;
                    }
                }
                mx[i] = fmaxf(mx[i], hnv[i]);
            } else if (!done[i]) {
                out[((long)samp[i] * 64 + seg[i]) * 1024 + dir * 512 + u] = mx[i];
                done[i] = true;
            }
        }

        // rotate pipelined xp regs
#pragma unroll
        for (int i = 0; i < 4; ++i) {
            cxr[i] = nxr[i]; cxz[i] = nxz[i]; cxn[i] = nxn[i];
            cpv[i] = npv[i]; cval[i] = nval[i];
        }
    }

#pragma unroll
    for (int i = 0; i < 4; ++i) {
        if (!done[i])  // full-length samples: flush last segment
            out[((long)samp[i] * 64 + seg[i]) * 1024 + dir * 512 + u] = mx[i];
        // final hidden: out[4194304 + dir*B*H + b*H + u]
        out[4194304 + dir * (B_ * H_) + samp[i] * H_ + u] = hm[i];
    }
}

// ---------- launch ----------
extern "C" void kernel_launch(void* const* d_in, const int* in_sizes, int n_in,
                              void* d_out, int out_size, void* d_ws, size_t ws_size,
                              hipStream_t stream) {
    const int*   seq    = (const int*)d_in[0];
    const int*   lens   = (const int*)d_in[1];
    const int*   layout = (const int*)d_in[3];
    const float* emb    = (const float*)d_in[4];
    const float* w_ih_f = (const float*)d_in[5];
    const float* w_hh_f = (const float*)d_in[6];
    const float* b_ih_f = (const float*)d_in[7];
    const float* b_hh_f = (const float*)d_in[8];
    const float* w_ih_b = (const float*)d_in[9];
    const float* w_hh_b = (const float*)d_in[10];
    const float* b_ih_b = (const float*)d_in[11];
    const float* b_hh_b = (const float*)d_in[12];
    float* out = (float*)d_out;
    char* ws = (char*)d_ws;

    u16* embb  = (u16*)(ws + EMBB_OFF);
    u16* wihbb = (u16*)(ws + WIHB_OFF);
    u16* whhbb = (u16*)(ws + WHHB_OFF);
    u16* hbuf  = (u16*)(ws + HBUF_OFF);
    int* cnt   = (int*)(ws + CNT_OFF);
    u16* xp    = (u16*)(ws + XP_OFF);

    prep_kernel<<<2048, 256, 0, stream>>>(emb, w_ih_f, w_hh_f, w_ih_b, w_hh_b,
                                          embb, wihbb, whhbb, hbuf, cnt);
    proj_kernel<<<256 * 24, 256, 0, stream>>>(seq, embb, wihbb, b_ih_f, b_ih_b, xp);
    rnn_kernel<<<256, 64, 0, stream>>>(lens, layout, whhbb, b_hh_f, b_hh_b,
                                       xp, hbuf, cnt, out);
}